// Round 12
// baseline (92.550 us; speedup 1.0000x reference)
//
#include <hip/hip_runtime.h>

// YOLO decode, MI355X. R11: barrier-free streaming with IN-REGISTER transpose.
// Wave = (b, a, 16-position strip). 5 rounds x (16 ch x 4 s) float4 loads,
// 4x4 cross-lane transpose (2-stage shfl_xor butterfly within 4 consecutive
// lanes), sigmoid, NT store: each conf store instr writes 16 COMPLETE 64B
// lines. No LDS tile, no staging barrier -> copy-ubench occupancy regime.
// Boxes/scores: p-linear contiguous via 384B LDS handoff (1 barrier).
// Exact divisions everywhere: 5776 = 16*361, 80 = 5*16 -> no tails.

#define NCLS 80
#define NA   3
#define BB   32
#define WW   76
#define HH   76
#define WH   (WW*HH)          // 5776
#define PP   (WH*NA)          // 17328
#define NSTRIP (WH/16)        // 361

typedef float f32x4 __attribute__((ext_vector_type(4)));

__global__ __launch_bounds__(192, 6) void yolo_kernel(
    const float* __restrict__ in,       // (B, 255, W, H)
    const float* __restrict__ anchors,  // [d*3 + a]
    float* __restrict__ boxes,          // (B, P, 4)
    float* __restrict__ conf,           // (B, P, 80)
    float* __restrict__ scores)         // (B, P)
{
    __shared__ float so_lds[48];
    __shared__ float rm_lds[48];

    const int t     = threadIdx.x;
    const int a     = t >> 6;           // wave = anchor
    const int l     = t & 63;
    const int bid   = blockIdx.x;
    const int strip = bid % NSTRIP;
    const int b     = bid / NSTRIP;
    const int s0    = strip * 16;

    const int sq = l >> 4;              // s-quad 0..3
    const int ci = l & 15;              // channel within round
    const int m  = (l >> 2) & 3;        // ch-quad within round
    const int i  = l & 3;               // lane within transpose group

    const float* aplane = in + ((size_t)b * 255 + a * 85) * WH;

    // post-transpose position owned by this lane
    const int sl = 4 * sq + i;          // 0..15
    const int s  = s0 + sl;

    // obj sigmoid for my position
    float so = 1.0f / (1.0f + __expf(-aplane[(size_t)4 * WH + s]));

    // hoisted head loads for the tail phase (t<48 only)
    float htx = 0.f, hty = 0.f, htw = 0.f, hth = 0.f;
    if (t < 48) {
        int aa = t % 3;
        int sh = s0 + t / 3;
        const float* hp = in + ((size_t)b * 255 + aa * 85) * WH + sh;
        htx = hp[0];
        hty = hp[(size_t)1 * WH];
        htw = hp[(size_t)2 * WH];
        hth = hp[(size_t)3 * WH];
    }

    // ---- load all 5 rounds: 16 B per lane per round, 64B/4-lane segments ----
    const float* base = aplane + (size_t)5 * WH + s0 + 4 * sq;
    float4 va0 = *reinterpret_cast<const float4*>(base + (size_t)(ci     ) * WH);
    float4 va1 = *reinterpret_cast<const float4*>(base + (size_t)(ci + 16) * WH);
    float4 va2 = *reinterpret_cast<const float4*>(base + (size_t)(ci + 32) * WH);
    float4 va3 = *reinterpret_cast<const float4*>(base + (size_t)(ci + 48) * WH);
    float4 va4 = *reinterpret_cast<const float4*>(base + (size_t)(ci + 64) * WH);

    float rm = -1e30f;
    size_t obase = ((size_t)b * PP + (size_t)s * NA + a) * NCLS + 4 * m;  // words

    // 4x4 transpose across lanes i=0..3: B[i][j] = M[j][i] via 2-stage butterfly
    #define ROUND(VA, C0) { \
        float v0 = VA.x, v1 = VA.y, v2 = VA.z, v3 = VA.w; \
        float s1_0 = __shfl_xor(v1, 1); \
        float s1_1 = __shfl_xor(v0, 1); \
        float s1_2 = __shfl_xor(v3, 1); \
        float s1_3 = __shfl_xor(v2, 1); \
        float n0 = (i & 1) ? s1_0 : v0; \
        float n1 = (i & 1) ? v1 : s1_1; \
        float n2 = (i & 1) ? s1_2 : v2; \
        float n3 = (i & 1) ? v3 : s1_3; \
        float s2_0 = __shfl_xor(n2, 2); \
        float s2_1 = __shfl_xor(n3, 2); \
        float s2_2 = __shfl_xor(n0, 2); \
        float s2_3 = __shfl_xor(n1, 2); \
        float o0 = (i & 2) ? s2_0 : n0; \
        float o1 = (i & 2) ? s2_1 : n1; \
        float o2 = (i & 2) ? n2 : s2_2; \
        float o3 = (i & 2) ? n3 : s2_3; \
        rm = fmaxf(rm, fmaxf(fmaxf(o0, o1), fmaxf(o2, o3))); \
        f32x4 oc; \
        oc.x = so / (1.0f + __expf(-o0)); \
        oc.y = so / (1.0f + __expf(-o1)); \
        oc.z = so / (1.0f + __expf(-o2)); \
        oc.w = so / (1.0f + __expf(-o3)); \
        __builtin_nontemporal_store(oc, \
            reinterpret_cast<f32x4*>(conf + obase + (C0))); \
    }

    ROUND(va0,  0)
    ROUND(va1, 16)
    ROUND(va2, 32)
    ROUND(va3, 48)
    ROUND(va4, 64)
    #undef ROUND

    // reduce raw-max across the 4 ch-quad lanes (m bits = lane bits 2..3)
    rm = fmaxf(rm, __shfl_xor(rm, 4));
    rm = fmaxf(rm, __shfl_xor(rm, 8));

    if (m == 0) {                        // one lane per (sl, a)
        so_lds[sl * 3 + a] = so;
        rm_lds[sl * 3 + a] = rm;
    }

    __syncthreads();

    // ---- boxes + scores: 48 p-linear threads, fully contiguous stores ----
    if (t < 48) {
        int aa = t % 3;
        int sh = s0 + t / 3;
        int w = sh / HH;
        int h = sh - w * HH;
        float sx = 1.0f / (1.0f + __expf(-htx));
        float sy = 1.0f / (1.0f + __expf(-hty));
        float bx = (sx + (float)w) * (1.0f / WW);
        float by = (sy + (float)h) * (1.0f / HH);
        float bw = __expf(htw) * anchors[aa];
        float bh = __expf(hth) * anchors[3 + aa];

        f32x4 bo = {bx - 0.5f * bw, by - 0.5f * bh,
                    bx + 0.5f * bw, by + 0.5f * bh};
        __builtin_nontemporal_store(bo,
            reinterpret_cast<f32x4*>(boxes + ((size_t)b * PP + s0 * 3 + t) * 4));

        float sc = so_lds[t] * (1.0f / (1.0f + __expf(-rm_lds[t])));
        __builtin_nontemporal_store(sc, scores + (size_t)b * PP + s0 * 3 + t);
    }
}

extern "C" void kernel_launch(void* const* d_in, const int* in_sizes, int n_in,
                              void* d_out, int out_size, void* d_ws, size_t ws_size,
                              hipStream_t stream) {
    const float* in      = (const float*)d_in[0];
    const float* anchors = (const float*)d_in[1];

    float* boxes  = (float*)d_out;                       // B*P*4
    float* conf   = boxes + (size_t)BB * PP * 4;         // B*P*80
    float* scores = conf + (size_t)BB * PP * NCLS;       // B*P

    int blocks = BB * NSTRIP;                            // 11552
    yolo_kernel<<<blocks, 192, 0, stream>>>(in, anchors, boxes, conf, scores);
}

// Round 13
// 85.854 us; speedup vs baseline: 1.0780x; 1.0780x over previous
//
#include <hip/hip_runtime.h>

// YOLO decode, MI355X. R12 = R11's read/transpose engine + R9b's store engine.
// Wave = (b, a, 16-position strip). 5 rounds x (16ch x 4s) float4 loads,
// in-register 4x4 shfl_xor transpose, sigmoid -> LDS cbuf[48][84] (16KB,
// 4-word row pad). One barrier. Store phase: q-linear over 960 quads =
// strip's conf span (15360B, 128B-line-aligned) as contiguous 1KB/wave-instr
// NT stores -- eliminates R11's +34MB partial-line write amplification while
// keeping its 4.5TB/s streaming regime (float4 reads, ~80% occupancy).

#define NCLS 80
#define NA   3
#define BB   32
#define WW   76
#define HH   76
#define WH   (WW*HH)          // 5776
#define PP   (WH*NA)          // 17328
#define NSTRIP (WH/16)        // 361
#define ROWW 84               // padded words per p-row in LDS (80+4)

typedef float f32x4 __attribute__((ext_vector_type(4)));

__global__ __launch_bounds__(192, 6) void yolo_kernel(
    const float* __restrict__ in,       // (B, 255, W, H)
    const float* __restrict__ anchors,  // [d*3 + a]
    float* __restrict__ boxes,          // (B, P, 4)
    float* __restrict__ conf,           // (B, P, 80)
    float* __restrict__ scores)         // (B, P)
{
    __shared__ float cbuf[48 * ROWW];   // 16128 B
    __shared__ float so_lds[48];
    __shared__ float rm_lds[48];

    const int t     = threadIdx.x;
    const int a     = t >> 6;           // wave = anchor
    const int l     = t & 63;
    const int bid   = blockIdx.x;
    const int strip = bid % NSTRIP;
    const int b     = bid / NSTRIP;
    const int s0    = strip * 16;

    const int sq = l >> 4;              // s-quad 0..3
    const int ci = l & 15;              // channel within round
    const int m  = (l >> 2) & 3;        // ch-quad within round
    const int i  = l & 3;               // lane within transpose group

    const float* aplane = in + ((size_t)b * 255 + a * 85) * WH;

    // post-transpose position owned by this lane
    const int sl = 4 * sq + i;          // 0..15
    const int s  = s0 + sl;
    const int pl = sl * 3 + a;          // local p-row 0..47

    // obj sigmoid for my position
    float so = 1.0f / (1.0f + __expf(-aplane[(size_t)4 * WH + s]));

    // hoisted head loads for the tail phase (t<48 only)
    float htx = 0.f, hty = 0.f, htw = 0.f, hth = 0.f;
    if (t < 48) {
        int aa = t % 3;
        int sh = s0 + t / 3;
        const float* hp = in + ((size_t)b * 255 + aa * 85) * WH + sh;
        htx = hp[0];
        hty = hp[(size_t)1 * WH];
        htw = hp[(size_t)2 * WH];
        hth = hp[(size_t)3 * WH];
    }

    // ---- load all 5 rounds: 16 B per lane per round ----
    const float* base = aplane + (size_t)5 * WH + s0 + 4 * sq;
    float4 va0 = *reinterpret_cast<const float4*>(base + (size_t)(ci     ) * WH);
    float4 va1 = *reinterpret_cast<const float4*>(base + (size_t)(ci + 16) * WH);
    float4 va2 = *reinterpret_cast<const float4*>(base + (size_t)(ci + 32) * WH);
    float4 va3 = *reinterpret_cast<const float4*>(base + (size_t)(ci + 48) * WH);
    float4 va4 = *reinterpret_cast<const float4*>(base + (size_t)(ci + 64) * WH);

    float rm = -1e30f;

    // 4x4 transpose across lanes i=0..3, then sigmoid -> LDS row pl
    #define ROUND(VA, R) { \
        float v0 = VA.x, v1 = VA.y, v2 = VA.z, v3 = VA.w; \
        float s1_0 = __shfl_xor(v1, 1); \
        float s1_1 = __shfl_xor(v0, 1); \
        float s1_2 = __shfl_xor(v3, 1); \
        float s1_3 = __shfl_xor(v2, 1); \
        float n0 = (i & 1) ? s1_0 : v0; \
        float n1 = (i & 1) ? v1 : s1_1; \
        float n2 = (i & 1) ? s1_2 : v2; \
        float n3 = (i & 1) ? v3 : s1_3; \
        float s2_0 = __shfl_xor(n2, 2); \
        float s2_1 = __shfl_xor(n3, 2); \
        float s2_2 = __shfl_xor(n0, 2); \
        float s2_3 = __shfl_xor(n1, 2); \
        float o0 = (i & 2) ? s2_0 : n0; \
        float o1 = (i & 2) ? s2_1 : n1; \
        float o2 = (i & 2) ? n2 : s2_2; \
        float o3 = (i & 2) ? n3 : s2_3; \
        rm = fmaxf(rm, fmaxf(fmaxf(o0, o1), fmaxf(o2, o3))); \
        float4 oc = make_float4(so / (1.0f + __expf(-o0)), \
                                so / (1.0f + __expf(-o1)), \
                                so / (1.0f + __expf(-o2)), \
                                so / (1.0f + __expf(-o3))); \
        *reinterpret_cast<float4*>(&cbuf[pl * ROWW + 16 * (R) + 4 * m]) = oc; \
    }

    ROUND(va0, 0)
    ROUND(va1, 1)
    ROUND(va2, 2)
    ROUND(va3, 3)
    ROUND(va4, 4)
    #undef ROUND

    // reduce raw-max across the 4 ch-quad lanes (m bits = lane bits 2..3)
    rm = fmaxf(rm, __shfl_xor(rm, 4));
    rm = fmaxf(rm, __shfl_xor(rm, 8));

    if (m == 0) {                        // one lane per (sl, a)
        so_lds[pl] = so;
        rm_lds[pl] = rm;
    }

    __syncthreads();

    // ---- conf store phase: 960 quads q-linear = contiguous line-aligned ----
    size_t cwbase = ((size_t)b * PP + (size_t)s0 * 3) * NCLS;   // words
    #pragma unroll
    for (int it = 0; it < 5; ++it) {
        int q = it * 192 + t;
        int p = q / 20;
        int u = q - p * 20;
        float4 v = *reinterpret_cast<const float4*>(&cbuf[p * ROWW + 4 * u]);
        f32x4 o = {v.x, v.y, v.z, v.w};
        __builtin_nontemporal_store(o,
            reinterpret_cast<f32x4*>(conf + cwbase + (size_t)q * 4));
    }

    // ---- boxes + scores: 48 p-linear threads, fully contiguous stores ----
    if (t < 48) {
        int aa = t % 3;
        int sh = s0 + t / 3;
        int w = sh / HH;
        int h = sh - w * HH;
        float sx = 1.0f / (1.0f + __expf(-htx));
        float sy = 1.0f / (1.0f + __expf(-hty));
        float bx = (sx + (float)w) * (1.0f / WW);
        float by = (sy + (float)h) * (1.0f / HH);
        float bw = __expf(htw) * anchors[aa];
        float bh = __expf(hth) * anchors[3 + aa];

        f32x4 bo = {bx - 0.5f * bw, by - 0.5f * bh,
                    bx + 0.5f * bw, by + 0.5f * bh};
        __builtin_nontemporal_store(bo,
            reinterpret_cast<f32x4*>(boxes + ((size_t)b * PP + s0 * 3 + t) * 4));

        float sc = so_lds[t] * (1.0f / (1.0f + __expf(-rm_lds[t])));
        __builtin_nontemporal_store(sc, scores + (size_t)b * PP + s0 * 3 + t);
    }
}

extern "C" void kernel_launch(void* const* d_in, const int* in_sizes, int n_in,
                              void* d_out, int out_size, void* d_ws, size_t ws_size,
                              hipStream_t stream) {
    const float* in      = (const float*)d_in[0];
    const float* anchors = (const float*)d_in[1];

    float* boxes  = (float*)d_out;                       // B*P*4
    float* conf   = boxes + (size_t)BB * PP * 4;         // B*P*80
    float* scores = conf + (size_t)BB * PP * NCLS;       // B*P

    int blocks = BB * NSTRIP;                            // 11552
    yolo_kernel<<<blocks, 192, 0, stream>>>(in, anchors, boxes, conf, scores);
}

// Round 14
// 69.787 us; speedup vs baseline: 1.3262x; 1.2302x over previous
//
#include <hip/hip_runtime.h>

// YOLO decode, MI355X. R13 = R7 pattern (TS=64: wide 256B read segments,
// FETCH ~98MB per the cross-round TS->FETCH law) + R9b occupancy (16 waves/CU)
// via 512-thread blocks, + R9b's NT wave-contiguous stores.
//   LDS 70.4KB -> 2 blocks/CU x 8 waves = 4 waves/SIMD (R7 had 2, R9b had 4).
// All access patterns byte-identical to the proven R5/R7/R9b core:
//   reads: 64 consecutive positions per plane per wave (256B segments);
//   LDS: cls[sl][PROW=260] transpose (row stride 1040B);
//   conf: q-linear wave-contiguous 16B NT stores (16 full lines/instr).

#define NCLS 80
#define NA   3
#define BB   32
#define WW   76
#define HH   76
#define WH   (WW*HH)          // 5776
#define PP   (WH*NA)          // 17328
#define TS   64               // positions per tile
#define NTILE ((WH + TS - 1) / TS)   // 91 (last tile: 16 valid)
#define PROW 260              // LDS row stride (words)

typedef float f32x4 __attribute__((ext_vector_type(4)));

__global__ __launch_bounds__(512, 4) void yolo_decode_kernel(
    const float* __restrict__ in,       // (B, 255, W, H)
    const float* __restrict__ anchors,  // (2, 3) flat: [d*3 + a]
    float* __restrict__ boxes,          // (B, P, 4)
    float* __restrict__ conf,           // (B, P, 80)
    float* __restrict__ scores)         // (B, P)
{
    __shared__ float  cls[TS * PROW];     // 66560 B
    __shared__ float  so_buf[TS * NA];    // 768 B
    __shared__ float4 box_buf[TS * NA];   // 3072 B

    const int t    = threadIdx.x;
    const int bid  = blockIdx.x;
    const int tile = bid % NTILE;
    const int b    = bid / NTILE;
    const int s0   = tile * TS;
    int valid = WH - s0; if (valid > TS) valid = TS;   // 64 or 16

    const float* bplane = in + (size_t)b * 255 * WH;

    // ---- head loads (t<192): wave per anchor, 64 consecutive sl ----
    int a_h   = t >> 6;                 // 0..2 for t<192
    int sl_h  = t & 63;
    int slc_h = sl_h < valid ? sl_h : valid - 1;
    float tx = 0.f, ty = 0.f, tw = 0.f, th = 0.f, to = 0.f;
    if (t < 192) {
        const float* hp = bplane + (size_t)(a_h * 85) * WH + s0 + slc_h;
        tx = hp[0];
        ty = hp[(size_t)1 * WH];
        tw = hp[(size_t)2 * WH];
        th = hp[(size_t)3 * WH];
        to = hp[(size_t)4 * WH];
    }

    // ---- stage 240 class channels transposed into LDS ----
    // unit = (ch-quad 0..59, sl 0..63): 3840 units, <=8/thread.
    // Per wave: qch constant, 64 consecutive sl -> one 256B segment per plane.
    #pragma unroll 4
    for (int it = 0; it < 8; ++it) {
        int u = it * 512 + t;
        if (u < 60 * TS) {
            int qch = u >> 6;              // 0..59
            int sl  = u & 63;
            int slc = sl < valid ? sl : valid - 1;
            int ch0 = qch * 4;             // never straddles an anchor
            int a   = ch0 / 80;
            int c0  = ch0 - a * 80;
            const float* gp = bplane + (size_t)(a * 85 + 5 + c0) * WH + s0 + slc;
            float v0 = gp[0];
            float v1 = gp[(size_t)1 * WH];
            float v2 = gp[(size_t)2 * WH];
            float v3 = gp[(size_t)3 * WH];
            *reinterpret_cast<float4*>(&cls[sl * PROW + ch0]) =
                make_float4(v0, v1, v2, v3);
        }
    }

    // ---- head compute -> LDS bufs (t<192) ----
    if (t < 192) {
        int s = s0 + slc_h;
        int w = s / HH;
        int h = s - w * HH;
        float sx = 1.0f / (1.0f + __expf(-tx));
        float sy = 1.0f / (1.0f + __expf(-ty));
        float bx = (sx + (float)w) * (1.0f / WW);
        float by = (sy + (float)h) * (1.0f / HH);
        float bw = __expf(tw) * anchors[a_h];
        float bh = __expf(th) * anchors[3 + a_h];
        int p = slc_h * 3 + a_h;           // clamped dups write identical data
        box_buf[p] = make_float4(bx - 0.5f * bw, by - 0.5f * bh,
                                 bx + 0.5f * bw, by + 0.5f * bh);
        so_buf[p] = 1.0f / (1.0f + __expf(-to));
    }

    __syncthreads();

    // ---- conf: 3840 quads q-linear => wave-contiguous 16B NT stores ----
    size_t cbase = ((size_t)b * PP + (size_t)s0 * 3) * NCLS;   // word offset
    int vq = valid * 60;
    #pragma unroll 4
    for (int it = 0; it < 8; ++it) {
        int q = it * 512 + t;
        if (q < vq) {
            int p  = q / 20;
            int u  = q - p * 20;
            int sl = p / 3;
            int a  = p - sl * 3;
            float4 tv = *reinterpret_cast<const float4*>(&cls[sl * PROW + a * 80 + u * 4]);
            float so = so_buf[p];
            f32x4 o;
            o.x = so / (1.0f + __expf(-tv.x));
            o.y = so / (1.0f + __expf(-tv.y));
            o.z = so / (1.0f + __expf(-tv.z));
            o.w = so / (1.0f + __expf(-tv.w));
            __builtin_nontemporal_store(o,
                reinterpret_cast<f32x4*>(conf + cbase + (size_t)q * 4));
        }
    }

    // ---- boxes + scores (t<192), wave-contiguous NT stores ----
    if (t < 192) {
        int p = t;
        if (p < valid * 3) {
            float4 bq = box_buf[p];
            f32x4 bo = {bq.x, bq.y, bq.z, bq.w};
            __builtin_nontemporal_store(bo,
                reinterpret_cast<f32x4*>(boxes + ((size_t)b * PP + s0 * 3 + p) * 4));
        }
        int sl = p / 3;
        int a  = p - sl * 3;
        float mx = -1e30f;
        #pragma unroll
        for (int c4 = 0; c4 < 20; ++c4) {
            float4 v = *reinterpret_cast<const float4*>(&cls[sl * PROW + a * 80 + c4 * 4]);
            mx = fmaxf(mx, fmaxf(fmaxf(v.x, v.y), fmaxf(v.z, v.w)));
        }
        float sc = so_buf[p] * (1.0f / (1.0f + __expf(-mx)));
        if (p < valid * 3) {
            __builtin_nontemporal_store(sc, scores + (size_t)b * PP + s0 * 3 + p);
        }
    }
}

extern "C" void kernel_launch(void* const* d_in, const int* in_sizes, int n_in,
                              void* d_out, int out_size, void* d_ws, size_t ws_size,
                              hipStream_t stream) {
    const float* in      = (const float*)d_in[0];
    const float* anchors = (const float*)d_in[1];

    float* boxes  = (float*)d_out;                       // B*P*4
    float* conf   = boxes + (size_t)BB * PP * 4;         // B*P*80
    float* scores = conf + (size_t)BB * PP * NCLS;       // B*P

    int blocks = BB * NTILE;                             // 2912
    yolo_decode_kernel<<<blocks, 512, 0, stream>>>(in, anchors, boxes, conf, scores);
}